// Round 18
// baseline (136.372 us; speedup 1.0000x reference)
//
#include <hip/hip_runtime.h>
#include <math.h>

#define NCLS 80
#define NA 8400
#define NB 32
#define NO 144
#define PRE_TOPK 1000
#define MAX_DET 100

typedef const __attribute__((address_space(1))) void g_void;
typedef __attribute__((address_space(3))) void l_void;

// ---------------- Kernel 1a: partial decode, 16-channel groups ----------------
// Block = (batch, group g of 16 channels, 1024-anchor tile). Stages [16][1024]
// (64 KB LDS): each channel-row read is 4 KB CONTIGUOUS (8x R16's 512 B) —
// tests the DRAM row-buffer-locality theory. g<4: DFL side g (softmax over its
// 16 bins) -> dist plane. g>=4: class chunk (max + first-occurrence argmax
// over 16 logits) -> partial (val,id) planes.
__global__ __launch_bounds__(512) void k_part(
    const float* __restrict__ p3, const float* __restrict__ p4, const float* __restrict__ p5,
    float* __restrict__ distp, float* __restrict__ clsv, int* __restrict__ clsi)
{
    __shared__ float s[16 * 1024];   // 64 KB
    int blk = blockIdx.x;
    int b = blk / 90;
    int r = blk - b * 90;
    int g = r / 10;                  // channel group 0..8
    int tile = r - g * 10;

    const float* src; int HW, a0, aoff;
    if (tile < 7)      { src = p3; HW = 6400; a0 = tile * 1024;       aoff = 0;    }
    else if (tile < 9) { src = p4; HW = 1600; a0 = (tile - 7) * 1024; aoff = 6400; }
    else               { src = p5; HW = 400;  a0 = 0;                 aoff = 8000; }
    int chbase = (g < 4) ? g * 16 : 64 + (g - 4) * 16;

    int t = threadIdx.x;
    int wv = t >> 6;
    // stage: 8 async 16B loads/lane; ch uniform per wave, LDS dest = base+lane*16
    #pragma unroll
    for (int i = 0; i < 8; ++i) {
        int flat = i * 512 + t;
        int ch = flat >> 8;          // wave-uniform (64-run never crosses 256)
        int q  = flat & 255;         // float4-quad within row
        int aq = a0 + q * 4; if (aq > HW - 4) aq = HW - 4;   // tail clamp (L2-absorbed)
        const float* gp = src + ((size_t)b * NO + chbase + ch) * HW + aq;
        float* lp = s + ch * 1024 + (wv & 3) * 256;          // wave-uniform base
        __builtin_amdgcn_global_load_lds((g_void*)gp, (l_void*)lp, 16, 0, 0);
    }
    __syncthreads();

    // compute: 2 anchors/thread; LDS stride 1024 -> bank = a%32, conflict-free
    #pragma unroll
    for (int h = 0; h < 2; ++h) {
        int a = t + h * 512;
        int ga = a0 + a;
        bool ok = ga < HW;
        if (g < 4) {
            float v[16];
            #pragma unroll
            for (int rr = 0; rr < 16; ++rr) v[rr] = s[rr * 1024 + a];
            float mm = v[0];
            #pragma unroll
            for (int rr = 1; rr < 16; ++rr) mm = fmaxf(mm, v[rr]);
            float sum = 0.f, d = 0.f;
            #pragma unroll
            for (int rr = 0; rr < 16; ++rr) {
                float e = __expf(v[rr] - mm);
                sum += e;
                d += e * (float)rr;
            }
            d *= 1.0f / sum;
            if (ok) distp[((size_t)g * NB + b) * NA + aoff + ga] = d;
        } else {
            float m = s[a]; int ii = 0;
            #pragma unroll
            for (int cc = 1; cc < 16; ++cc) {
                float x = s[cc * 1024 + a];
                if (x > m) { m = x; ii = cc; }
            }
            if (ok) {
                size_t o = ((size_t)(g - 4) * NB + b) * NA + aoff + ga;
                clsv[o] = m;
                clsi[o] = (g - 4) * 16 + ii;
            }
        }
    }
}

// ---------------- Kernel 1b: combine partials -> conf/clsid/box ----------------
__global__ __launch_bounds__(256) void k_comb(
    const float* __restrict__ distp, const float* __restrict__ clsv, const int* __restrict__ clsi,
    float* __restrict__ conf, int* __restrict__ clsid, float* __restrict__ box)
{
    int gid = blockIdx.x * 256 + threadIdx.x;
    if (gid >= NB * NA) return;
    int b = gid / NA;
    int ga = gid - b * NA;

    float d0 = distp[((size_t)0 * NB + b) * NA + ga];
    float d1 = distp[((size_t)1 * NB + b) * NA + ga];
    float d2 = distp[((size_t)2 * NB + b) * NA + ga];
    float d3 = distp[((size_t)3 * NB + b) * NA + ga];

    // ascending-group strict-> combine: global first-occurrence argmax
    float bm = clsv[((size_t)0 * NB + b) * NA + ga];
    int bid   = clsi[((size_t)0 * NB + b) * NA + ga];
    #pragma unroll
    for (int g = 1; g < 5; ++g) {
        float m = clsv[((size_t)g * NB + b) * NA + ga];
        int  id = clsi[((size_t)g * NB + b) * NA + ga];
        if (m > bm) { bm = m; bid = id; }
    }
    float conf_v = 1.0f / (1.0f + __expf(-bm));   // sigmoid(max)==max(sigmoid)

    int pos, WDIM; float S;
    if (ga < 6400)      { pos = ga;        WDIM = 80; S = 8.f;  }
    else if (ga < 8000) { pos = ga - 6400; WDIM = 40; S = 16.f; }
    else                { pos = ga - 8000; WDIM = 20; S = 32.f; }

    float ax = (float)(pos % WDIM) + 0.5f;
    float ay = (float)(pos / WDIM) + 0.5f;
    float x1 = ax - d0, y1 = ay - d1;
    float x2 = ax + d2, y2 = ay + d3;
    float cx = ((x1 + x2) * 0.5f) * S;
    float cy = ((y1 + y2) * 0.5f) * S;
    float ww = (x2 - x1) * S;
    float hh = (y2 - y1) * S;

    conf[gid]  = conf_v;
    clsid[gid] = bid;
    *(float4*)(box + (size_t)gid * 4) = make_float4(cx, cy, ww, hh);
}

// ---------------- Kernel 2: exact stable top-1000 per batch (R14) ----------
__device__ __forceinline__ uint32_t ord_bits(float f) {
    uint32_t u = __float_as_uint(f);
    return (u & 0x80000000u) ? ~u : (u | 0x80000000u);
}

__global__ __launch_bounds__(1024) void k_select(
    const float* __restrict__ conf, const float* __restrict__ box, const int* __restrict__ clsid,
    float* __restrict__ topv, float* __restrict__ bxyxy, int* __restrict__ topcls)
{
    int b = blockIdx.x;
    int t = threadIdx.x;
    int lane = t & 63;

    __shared__ uint32_t hist[256];
    __shared__ uint64_t sbuf[1024];      // 8 KB
    __shared__ uint32_t s_prefix;
    __shared__ int s_k;
    __shared__ int s_cnt;

    // 9 keys/thread in registers (static indexing, full unroll)
    const float* cf = conf + (size_t)b * NA;
    uint32_t kr[9];
    #pragma unroll
    for (int p = 0; p < 9; ++p) {
        int i = t + p * 1024;
        uint32_t k = 0;
        if (i < NA) {
            float c = cf[i];
            float cm = (c > 0.25f) ? c : -1.0f;
            k = ord_bits(cm);
        }
        kr[p] = k;
    }
    if (t == 0) { s_prefix = 0; s_k = PRE_TOPK; s_cnt = 0; }
    sbuf[t] = 0;
    __syncthreads();

    // 4 radix passes over 32-bit ord(conf); wave-aggregated hist atomics
    for (int pass = 0; pass < 4; ++pass) {
        int shift = 24 - 8 * pass;
        if (t < 256) hist[t] = 0;
        __syncthreads();
        uint32_t prefix = s_prefix;
        int k = s_k;
        #pragma unroll
        for (int p = 0; p < 9; ++p) {
            int i = t + p * 1024;
            uint32_t key = kr[p];
            bool match = (i < NA) &&
                         ((pass == 0) || (((key ^ prefix) >> (32 - 8 * pass)) == 0));
            uint32_t d = (key >> shift) & 255u;
            if (match) {
                uint64_t m = __ballot(1);
                #pragma unroll
                for (int bb = 0; bb < 8; ++bb) {
                    uint64_t bal = __ballot((d >> bb) & 1u);
                    m &= ((d >> bb) & 1u) ? bal : ~bal;
                }
                if ((m & ((1ull << lane) - 1ull)) == 0ull)
                    atomicAdd(&hist[d], (uint32_t)__popcll(m));
            }
        }
        __syncthreads();
        if (t < 64) {   // wave-0 suffix-scan digit selection
            uint32_t h0 = hist[4 * t + 0], h1 = hist[4 * t + 1];
            uint32_t h2 = hist[4 * t + 2], h3 = hist[4 * t + 3];
            uint32_t part = h0 + h1 + h2 + h3;
            uint32_t s = part;
            #pragma unroll
            for (int off = 1; off < 64; off <<= 1) {
                uint32_t v = __shfl_down(s, off);
                if (t + off < 64) s += v;
            }
            uint32_t cb3 = s - part;
            uint32_t cb2 = cb3 + h3;
            uint32_t cb1 = cb2 + h2;
            uint32_t cb0 = cb1 + h1;
            uint32_t ku = (uint32_t)k;
            if (cb3 < ku && ku <= cb3 + h3) { s_k = k - (int)cb3; s_prefix = prefix | ((uint32_t)(4 * t + 3) << shift); }
            if (cb2 < ku && ku <= cb2 + h2) { s_k = k - (int)cb2; s_prefix = prefix | ((uint32_t)(4 * t + 2) << shift); }
            if (cb1 < ku && ku <= cb1 + h1) { s_k = k - (int)cb1; s_prefix = prefix | ((uint32_t)(4 * t + 1) << shift); }
            if (cb0 < ku && ku <= cb0 + h0) { s_k = k - (int)cb0; s_prefix = prefix | ((uint32_t)(4 * t + 0) << shift); }
        }
        __syncthreads();
    }

    // compact kr >= kstar (greater + equal-conf ties), build 46-bit keys
    uint32_t kstar = s_prefix;
    #pragma unroll
    for (int p = 0; p < 9; ++p) {
        int i = t + p * 1024;
        uint32_t key = kr[p];
        if (i < NA && key >= kstar) {
            int pos = atomicAdd(&s_cnt, 1);
            if (pos < 1024) sbuf[pos] = ((uint64_t)key << 14) | (uint64_t)(16383 - i);
        }
    }
    __syncthreads();

    // bitonic sort 1024 descending by (conf, -index); register-resident,
    // j<64 stages via __shfl_xor (no barrier), j>=64 via LDS.
    uint64_t v = sbuf[t];
    for (int k = 2; k <= 1024; k <<= 1) {
        for (int j = k >> 1; j > 0; j >>= 1) {
            uint64_t o;
            if (j >= 64) {
                sbuf[t] = v;
                __syncthreads();
                o = sbuf[t ^ j];
                __syncthreads();
            } else {
                o = __shfl_xor((unsigned long long)v, j);
            }
            bool desc  = ((t & k) == 0);
            bool lower = ((t & j) == 0);
            v = (desc == lower) ? (v > o ? v : o) : (v < o ? v : o);
        }
    }

    if (t < PRE_TOPK) {
        uint64_t key = v;
        uint32_t u = (uint32_t)(key >> 14);
        uint32_t fb = (u & 0x80000000u) ? (u ^ 0x80000000u) : ~u;
        float val = __uint_as_float(fb);
        int idx = 16383 - (int)(key & 16383u);
        size_t g = (size_t)b * NA + idx;
        float4 bx = *(const float4*)(box + g * 4);
        float cx = bx.x, cy = bx.y, w = bx.z, h = bx.w;
        size_t o = (size_t)b * PRE_TOPK + t;
        topv[o] = val;
        *(float4*)(bxyxy + o * 4) = make_float4(cx - w * 0.5f, cy - h * 0.5f,
                                                cx + w * 0.5f, cy + h * 0.5f);
        topcls[o] = clsid[g];
    }
}

// ---------------- Kernel 3: pairwise IoU bitmask (full GPU, unchanged) ------
__device__ __forceinline__ int bslot(int j) { return j + (j >> 6); }

__global__ __launch_bounds__(256) void k_iou(
    const float* __restrict__ bxyxy, unsigned long long* __restrict__ mask)
{
    __shared__ float4 boxes[PRE_TOPK + 16];   // padded: lane stride 65 float4 -> 2-way (free)
    int b = blockIdx.y;
    int t = threadIdx.x;
    const float4* bp = (const float4*)(bxyxy + (size_t)b * PRE_TOPK * 4);
    for (int i = t; i < PRE_TOPK; i += 256) boxes[bslot(i)] = bp[i];
    __syncthreads();

    int r_local = t >> 4, w = t & 15;
    int row = blockIdx.x * 16 + r_local;
    if (row >= PRE_TOPK) return;

    float4 bi = boxes[bslot(row)];
    float area_i = (bi.z - bi.x) * (bi.w - bi.y);
    unsigned long long bits = 0;
    int j0 = w * 64;
    #pragma unroll 4
    for (int jj = 0; jj < 64; ++jj) {
        int j = j0 + jj;
        if (j >= PRE_TOPK) break;
        if (j <= row) continue;
        float4 bj = boxes[bslot(j)];
        float lx = fmaxf(bi.x, bj.x), ly = fmaxf(bi.y, bj.y);
        float rx = fminf(bi.z, bj.z), ry = fminf(bi.w, bj.w);
        float iw = fmaxf(rx - lx, 0.f), ih = fmaxf(ry - ly, 0.f);
        float inter = iw * ih;
        float area_j = (bj.z - bj.x) * (bj.w - bj.y);
        float iou = inter / (area_i + area_j - inter + 1e-7f);
        if (iou > 0.45f) bits |= (1ull << jj);
    }
    mask[((size_t)b * PRE_TOPK + row) * 16 + w] = bits;
}

// ---------------- Kernel 4: leader-jump NMS walk + emit (unchanged) --------
__global__ __launch_bounds__(1024) void k_nms(
    const unsigned long long* __restrict__ mask, const float* __restrict__ topv,
    const float* __restrict__ bxyxy, const int* __restrict__ topcls,
    float* __restrict__ out)
{
    int b = blockIdx.x;
    int t = threadIdx.x;

    __shared__ __align__(16) unsigned long long smask[PRE_TOPK * 16];  // 128 KB
    __shared__ float sv[PRE_TOPK];
    __shared__ unsigned long long s_valid[16];
    __shared__ int kept[MAX_DET];
    __shared__ int s_cnt;

    for (int i = t; i < PRE_TOPK; i += 1024) sv[i] = topv[(size_t)b * PRE_TOPK + i];
    {
        const ulonglong2* src = (const ulonglong2*)(mask + (size_t)b * PRE_TOPK * 16);
        ulonglong2* dst = (ulonglong2*)smask;
        for (int i = t; i < PRE_TOPK * 8; i += 1024) dst[i] = src[i];
    }
    __syncthreads();

    {
        bool pred = (t < PRE_TOPK) && (sv[t] > 0.0f);
        unsigned long long bal = __ballot(pred);
        if ((t & 63) == 0) s_valid[t >> 6] = bal;
    }
    __syncthreads();

    if (t < 64) {   // wave 0: leader-jump walk (one iteration per KEPT box)
        int w = t;
        unsigned long long supp = 0;
        unsigned long long valid = (w < 16) ? s_valid[w] : 0ull;
        int base = w * 64;
        int cur = -1;
        int cnt = 0;
        while (cnt < MAX_DET) {
            unsigned long long gt;
            if (cur < base)            gt = ~0ull;
            else if (cur - base >= 63) gt = 0ull;
            else                       gt = (~0ull) << (cur - base + 1);
            unsigned long long cand = valid & ~supp & gt;
            int idx = cand ? (base + __builtin_ctzll(cand)) : 0x7FFFFFFF;
            #pragma unroll
            for (int off = 8; off >= 1; off >>= 1) {
                int o = __shfl_xor(idx, off);
                idx = (o < idx) ? o : idx;
            }
            int nxt = __shfl(idx, 0);
            if (nxt == 0x7FFFFFFF) break;
            if (t == 0) kept[cnt] = nxt;
            ++cnt;
            if (w < 16) supp |= smask[nxt * 16 + w];
            cur = nxt;
        }
        if (t == 0) s_cnt = cnt;
    }
    __syncthreads();

    int cnt = s_cnt; if (cnt > MAX_DET) cnt = MAX_DET;
    if (t == 0) out[b] = (float)cnt;                       // num_dets (B,1)
    if (t < MAX_DET) {
        bool valid = t < cnt;
        float bx0 = 0.f, bx1 = 0.f, bx2 = 0.f, bx3 = 0.f, sc = 0.f, cl = 0.f;
        if (valid) {
            int p = kept[t];
            size_t o = (size_t)b * PRE_TOPK + p;
            float4 bb = *(const float4*)(bxyxy + o * 4);
            bx0 = bb.x; bx1 = bb.y; bx2 = bb.z; bx3 = bb.w;
            sc = sv[p];
            cl = (float)topcls[o];
        }
        size_t db = 32 + ((size_t)b * MAX_DET + t) * 4;
        out[db + 0] = bx0; out[db + 1] = bx1; out[db + 2] = bx2; out[db + 3] = bx3;
        out[32 + 12800 + (size_t)b * MAX_DET + t] = sc;    // det_scores
        out[32 + 16000 + (size_t)b * MAX_DET + t] = cl;    // det_classes
    }
}

// ---------------- launch ----------------
extern "C" void kernel_launch(void* const* d_in, const int* in_sizes, int n_in,
                              void* d_out, int out_size, void* d_ws, size_t ws_size,
                              hipStream_t stream)
{
    const float* p3 = (const float*)d_in[0];
    const float* p4 = (const float*)d_in[1];
    const float* p5 = (const float*)d_in[2];
    float* out = (float*)d_out;

    char* ws = (char*)d_ws;
    size_t off_mask = 0;                                       // 32*1000*16*8 = 4,096,000
    size_t off_conf = off_mask + (size_t)NB * PRE_TOPK * 16 * 8;
    size_t off_cls  = off_conf + (size_t)NB * NA * 4;
    size_t off_box  = off_cls  + (size_t)NB * NA * 4;
    size_t off_topv = off_box  + (size_t)NB * NA * 4 * 4;
    size_t off_topc = off_topv + (size_t)NB * PRE_TOPK * 4;
    size_t off_bx   = off_topc + (size_t)NB * PRE_TOPK * 4;
    size_t off_dst  = off_bx   + (size_t)NB * PRE_TOPK * 4 * 4;
    size_t off_clv  = off_dst  + (size_t)4 * NB * NA * 4;
    size_t off_cli  = off_clv  + (size_t)5 * NB * NA * 4;

    unsigned long long* mask = (unsigned long long*)(ws + off_mask);
    float* conf   = (float*)(ws + off_conf);
    int*   clsid  = (int*)(ws + off_cls);
    float* box    = (float*)(ws + off_box);
    float* topv   = (float*)(ws + off_topv);
    int*   topcls = (int*)(ws + off_topc);
    float* bxyxy  = (float*)(ws + off_bx);
    float* distp  = (float*)(ws + off_dst);
    float* clsv   = (float*)(ws + off_clv);
    int*   clsi   = (int*)(ws + off_cli);

    k_part<<<NB * 90, 512, 0, stream>>>(p3, p4, p5, distp, clsv, clsi);
    k_comb<<<(NB * NA + 255) / 256, 256, 0, stream>>>(distp, clsv, clsi, conf, clsid, box);
    k_select<<<NB, 1024, 0, stream>>>(conf, box, clsid, topv, bxyxy, topcls);
    k_iou<<<dim3((PRE_TOPK + 15) / 16, NB), 256, 0, stream>>>(bxyxy, mask);
    k_nms<<<NB, 1024, 0, stream>>>(mask, topv, bxyxy, topcls, out);
}

// Round 19
// 130.292 us; speedup vs baseline: 1.0467x; 1.0467x over previous
//
#include <hip/hip_runtime.h>
#include <math.h>

#define NCLS 80
#define NA 8400
#define NB 32
#define NO 144
#define PRE_TOPK 1000
#define MAX_DET 100

typedef const __attribute__((address_space(1))) void g_void;
typedef __attribute__((address_space(3))) void l_void;

// ---------------- Kernel 1: decode with async global->LDS staging (R17) ----
template<int HW, int WDIM, int S>
__device__ __forceinline__ void decode_blk(
    const float* __restrict__ src, int b, int a0, int aoff,
    float* __restrict__ conf, int* __restrict__ clsid, float* __restrict__ box,
    float* s_tile)
{
    int t = threadIdx.x;              // 0..511

    // ---- stage 144 ch x 128 anchors: 9 async 16B loads/lane ----
    {
        int wv   = t >> 6;                         // wave 0..7
        int lane = t & 63;
        int chl  = wv * 2 + (lane >> 5);           // per-lane channel
        int aq   = (lane & 31) * 4;
        int aqc  = a0 + aq; if (aqc > HW - 4) aqc = HW - 4;   // tail clamp
        const float* gsrc = src + ((size_t)b * NO) * HW + aqc;
        #pragma unroll
        for (int i = 0; i < 9; ++i) {
            const float* gp = gsrc + (size_t)(chl + 16 * i) * HW;
            float* lp = &s_tile[(wv * 2 + 16 * i) * 128];     // wave-uniform base
            __builtin_amdgcn_global_load_lds((g_void*)gp, (l_void*)lp, 16, 0, 0);
        }
    }
    __syncthreads();

    // ---- compute: part p, anchor a (bank-free: stride 128) ----
    int p = t >> 7;                   // 0..3
    int a = t & 127;

    float v[16];
    #pragma unroll
    for (int r = 0; r < 16; ++r) v[r] = s_tile[(p * 16 + r) * 128 + a];
    float mm = v[0];
    #pragma unroll
    for (int r = 1; r < 16; ++r) mm = fmaxf(mm, v[r]);
    float sum = 0.f, d = 0.f;
    #pragma unroll
    for (int r = 0; r < 16; ++r) {
        float e = __expf(v[r] - mm);
        sum += e;
        d += e * (float)r;
    }
    d *= 1.0f / sum;

    float c[20];
    #pragma unroll
    for (int cc = 0; cc < 20; ++cc) c[cc] = s_tile[(64 + p * 20 + cc) * 128 + a];
    float m = c[0]; int ii = 0;
    #pragma unroll
    for (int cc = 1; cc < 20; ++cc) if (c[cc] > m) { m = c[cc]; ii = cc; }

    __syncthreads();   // all tile reads done; overlay safe

    float* s_dfl = s_tile;             // [128*5]
    float* s_mx  = s_tile + 640;       // [128*5]
    int*   s_id  = (int*)(s_tile + 1280);
    s_dfl[a * 5 + p] = d;
    s_mx[a * 5 + p]  = m;
    s_id[a * 5 + p]  = p * 20 + ii;
    __syncthreads();

    // waves 0-1 combine and emit 128 anchors
    if (t < 128 && a0 + t < HW) {
        int pos2 = a0 + t;
        float d0 = s_dfl[t * 5 + 0], d1 = s_dfl[t * 5 + 1];
        float d2 = s_dfl[t * 5 + 2], d3 = s_dfl[t * 5 + 3];
        float bm = s_mx[t * 5 + 0]; int bid = s_id[t * 5 + 0];
        float m1 = s_mx[t * 5 + 1]; if (m1 > bm) { bm = m1; bid = s_id[t * 5 + 1]; }
        float m2 = s_mx[t * 5 + 2]; if (m2 > bm) { bm = m2; bid = s_id[t * 5 + 2]; }
        float m3 = s_mx[t * 5 + 3]; if (m3 > bm) { bm = m3; bid = s_id[t * 5 + 3]; }
        float conf_v = 1.0f / (1.0f + __expf(-bm));   // sigmoid(max)==max(sigmoid)

        float ax = (float)(pos2 % WDIM) + 0.5f;
        float ay = (float)(pos2 / WDIM) + 0.5f;
        float x1 = ax - d0, y1 = ay - d1;
        float x2 = ax + d2, y2 = ay + d3;
        float cx = ((x1 + x2) * 0.5f) * (float)S;
        float cy = ((y1 + y2) * 0.5f) * (float)S;
        float ww = (x2 - x1) * (float)S;
        float hh = (y2 - y1) * (float)S;

        size_t gid = (size_t)b * NA + aoff + pos2;
        conf[gid]  = conf_v;
        clsid[gid] = bid;
        *(float4*)(box + gid * 4) = make_float4(cx, cy, ww, hh);
    }
}

// per batch: 50 blocks (p3) + 13 (p4) + 4 (p5) = 67
__global__ __launch_bounds__(512) void k_decode(
    const float* __restrict__ p3, const float* __restrict__ p4, const float* __restrict__ p5,
    float* __restrict__ conf, int* __restrict__ clsid, float* __restrict__ box)
{
    __shared__ float s_tile[NO * 128];   // 73,728 B
    int blk = blockIdx.x;
    int b = blk / 67;
    int r = blk - b * 67;
    if (r < 50)       decode_blk<6400, 80, 8>(p3, b, r * 128, 0, conf, clsid, box, s_tile);
    else if (r < 63)  decode_blk<1600, 40, 16>(p4, b, (r - 50) * 128, 6400, conf, clsid, box, s_tile);
    else              decode_blk<400, 20, 32>(p5, b, (r - 63) * 128, 8000, conf, clsid, box, s_tile);
}

// ---------------- Kernel 2: exact stable top-1000 per batch (R14) ----------
__device__ __forceinline__ uint32_t ord_bits(float f) {
    uint32_t u = __float_as_uint(f);
    return (u & 0x80000000u) ? ~u : (u | 0x80000000u);
}

__global__ __launch_bounds__(1024) void k_select(
    const float* __restrict__ conf, const float* __restrict__ box, const int* __restrict__ clsid,
    float* __restrict__ topv, float* __restrict__ bxyxy, int* __restrict__ topcls)
{
    int b = blockIdx.x;
    int t = threadIdx.x;
    int lane = t & 63;

    __shared__ uint32_t hist[256];
    __shared__ uint64_t sbuf[1024];      // 8 KB
    __shared__ uint32_t s_prefix;
    __shared__ int s_k;
    __shared__ int s_cnt;

    // 9 keys/thread in registers (static indexing, full unroll)
    const float* cf = conf + (size_t)b * NA;
    uint32_t kr[9];
    #pragma unroll
    for (int p = 0; p < 9; ++p) {
        int i = t + p * 1024;
        uint32_t k = 0;
        if (i < NA) {
            float c = cf[i];
            float cm = (c > 0.25f) ? c : -1.0f;
            k = ord_bits(cm);
        }
        kr[p] = k;
    }
    if (t == 0) { s_prefix = 0; s_k = PRE_TOPK; s_cnt = 0; }
    sbuf[t] = 0;
    __syncthreads();

    // 4 radix passes over 32-bit ord(conf); wave-aggregated hist atomics
    for (int pass = 0; pass < 4; ++pass) {
        int shift = 24 - 8 * pass;
        if (t < 256) hist[t] = 0;
        __syncthreads();
        uint32_t prefix = s_prefix;
        int k = s_k;
        #pragma unroll
        for (int p = 0; p < 9; ++p) {
            int i = t + p * 1024;
            uint32_t key = kr[p];
            bool match = (i < NA) &&
                         ((pass == 0) || (((key ^ prefix) >> (32 - 8 * pass)) == 0));
            uint32_t d = (key >> shift) & 255u;
            if (match) {
                uint64_t m = __ballot(1);
                #pragma unroll
                for (int bb = 0; bb < 8; ++bb) {
                    uint64_t bal = __ballot((d >> bb) & 1u);
                    m &= ((d >> bb) & 1u) ? bal : ~bal;
                }
                if ((m & ((1ull << lane) - 1ull)) == 0ull)
                    atomicAdd(&hist[d], (uint32_t)__popcll(m));
            }
        }
        __syncthreads();
        if (t < 64) {   // wave-0 suffix-scan digit selection
            uint32_t h0 = hist[4 * t + 0], h1 = hist[4 * t + 1];
            uint32_t h2 = hist[4 * t + 2], h3 = hist[4 * t + 3];
            uint32_t part = h0 + h1 + h2 + h3;
            uint32_t s = part;
            #pragma unroll
            for (int off = 1; off < 64; off <<= 1) {
                uint32_t v = __shfl_down(s, off);
                if (t + off < 64) s += v;
            }
            uint32_t cb3 = s - part;
            uint32_t cb2 = cb3 + h3;
            uint32_t cb1 = cb2 + h2;
            uint32_t cb0 = cb1 + h1;
            uint32_t ku = (uint32_t)k;
            if (cb3 < ku && ku <= cb3 + h3) { s_k = k - (int)cb3; s_prefix = prefix | ((uint32_t)(4 * t + 3) << shift); }
            if (cb2 < ku && ku <= cb2 + h2) { s_k = k - (int)cb2; s_prefix = prefix | ((uint32_t)(4 * t + 2) << shift); }
            if (cb1 < ku && ku <= cb1 + h1) { s_k = k - (int)cb1; s_prefix = prefix | ((uint32_t)(4 * t + 1) << shift); }
            if (cb0 < ku && ku <= cb0 + h0) { s_k = k - (int)cb0; s_prefix = prefix | ((uint32_t)(4 * t + 0) << shift); }
        }
        __syncthreads();
    }

    // compact kr >= kstar (greater + equal-conf ties), build 46-bit keys
    uint32_t kstar = s_prefix;
    #pragma unroll
    for (int p = 0; p < 9; ++p) {
        int i = t + p * 1024;
        uint32_t key = kr[p];
        if (i < NA && key >= kstar) {
            int pos = atomicAdd(&s_cnt, 1);
            if (pos < 1024) sbuf[pos] = ((uint64_t)key << 14) | (uint64_t)(16383 - i);
        }
    }
    __syncthreads();

    // bitonic sort 1024 descending by (conf, -index); register-resident,
    // j<64 stages via __shfl_xor (no barrier), j>=64 via LDS.
    uint64_t v = sbuf[t];
    for (int k = 2; k <= 1024; k <<= 1) {
        for (int j = k >> 1; j > 0; j >>= 1) {
            uint64_t o;
            if (j >= 64) {
                sbuf[t] = v;
                __syncthreads();
                o = sbuf[t ^ j];
                __syncthreads();
            } else {
                o = __shfl_xor((unsigned long long)v, j);
            }
            bool desc  = ((t & k) == 0);
            bool lower = ((t & j) == 0);
            v = (desc == lower) ? (v > o ? v : o) : (v < o ? v : o);
        }
    }

    if (t < PRE_TOPK) {
        uint64_t key = v;
        uint32_t u = (uint32_t)(key >> 14);
        uint32_t fb = (u & 0x80000000u) ? (u ^ 0x80000000u) : ~u;
        float val = __uint_as_float(fb);
        int idx = 16383 - (int)(key & 16383u);
        size_t g = (size_t)b * NA + idx;
        float4 bx = *(const float4*)(box + g * 4);
        float cx = bx.x, cy = bx.y, w = bx.z, h = bx.w;
        size_t o = (size_t)b * PRE_TOPK + t;
        topv[o] = val;
        *(float4*)(bxyxy + o * 4) = make_float4(cx - w * 0.5f, cy - h * 0.5f,
                                                cx + w * 0.5f, cy + h * 0.5f);
        topcls[o] = clsid[g];
    }
}

// ---------------- Kernel 3: pairwise IoU bitmask (full GPU, unchanged) ------
__device__ __forceinline__ int bslot(int j) { return j + (j >> 6); }

__global__ __launch_bounds__(256) void k_iou(
    const float* __restrict__ bxyxy, unsigned long long* __restrict__ mask)
{
    __shared__ float4 boxes[PRE_TOPK + 16];   // padded: lane stride 65 float4 -> 2-way (free)
    int b = blockIdx.y;
    int t = threadIdx.x;
    const float4* bp = (const float4*)(bxyxy + (size_t)b * PRE_TOPK * 4);
    for (int i = t; i < PRE_TOPK; i += 256) boxes[bslot(i)] = bp[i];
    __syncthreads();

    int r_local = t >> 4, w = t & 15;
    int row = blockIdx.x * 16 + r_local;
    if (row >= PRE_TOPK) return;

    float4 bi = boxes[bslot(row)];
    float area_i = (bi.z - bi.x) * (bi.w - bi.y);
    unsigned long long bits = 0;
    int j0 = w * 64;
    #pragma unroll 4
    for (int jj = 0; jj < 64; ++jj) {
        int j = j0 + jj;
        if (j >= PRE_TOPK) break;
        if (j <= row) continue;
        float4 bj = boxes[bslot(j)];
        float lx = fmaxf(bi.x, bj.x), ly = fmaxf(bi.y, bj.y);
        float rx = fminf(bi.z, bj.z), ry = fminf(bi.w, bj.w);
        float iw = fmaxf(rx - lx, 0.f), ih = fmaxf(ry - ly, 0.f);
        float inter = iw * ih;
        float area_j = (bj.z - bj.x) * (bj.w - bj.y);
        float iou = inter / (area_i + area_j - inter + 1e-7f);
        if (iou > 0.45f) bits |= (1ull << jj);
    }
    mask[((size_t)b * PRE_TOPK + row) * 16 + w] = bits;
}

// ---------------- Kernel 4: leader-jump NMS walk + emit --------------------
// Mask staged via async global_load_lds (wave-uniform base + lane*16B; the
// __syncthreads drains vmcnt) — removes the VGPR round-trip of the old copy.
__global__ __launch_bounds__(1024) void k_nms(
    const unsigned long long* __restrict__ mask, const float* __restrict__ topv,
    const float* __restrict__ bxyxy, const int* __restrict__ topcls,
    float* __restrict__ out)
{
    int b = blockIdx.x;
    int t = threadIdx.x;

    __shared__ __align__(16) unsigned long long smask[PRE_TOPK * 16];  // 128 KB
    __shared__ float sv[PRE_TOPK];
    __shared__ unsigned long long s_valid[16];
    __shared__ int kept[MAX_DET];
    __shared__ int s_cnt;

    for (int i = t; i < PRE_TOPK; i += 1024) sv[i] = topv[(size_t)b * PRE_TOPK + i];
    {
        // 8000 x 16B chunks, 1024 threads -> 8 rounds per thread (last partial)
        int wv = t >> 6;                    // wave 0..15
        const char* gbase = (const char*)(mask + (size_t)b * PRE_TOPK * 16);
        #pragma unroll
        for (int i = 0; i < 8; ++i) {
            int chunk = i * 1024 + t;       // 16B-chunk index
            if (chunk < PRE_TOPK * 2) {
                const char* gp = gbase + (size_t)chunk * 16;
                // wave-uniform LDS base for this round: (i*1024 + wv*64) chunks
                char* lp = (char*)smask + ((size_t)i * 1024 + wv * 64) * 16;
                __builtin_amdgcn_global_load_lds((g_void*)gp, (l_void*)lp, 16, 0, 0);
            }
        }
    }
    __syncthreads();

    {
        bool pred = (t < PRE_TOPK) && (sv[t] > 0.0f);
        unsigned long long bal = __ballot(pred);
        if ((t & 63) == 0) s_valid[t >> 6] = bal;
    }
    __syncthreads();

    if (t < 64) {   // wave 0: leader-jump walk (one iteration per KEPT box)
        int w = t;
        unsigned long long supp = 0;
        unsigned long long valid = (w < 16) ? s_valid[w] : 0ull;
        int base = w * 64;
        int cur = -1;
        int cnt = 0;
        while (cnt < MAX_DET) {
            unsigned long long gt;
            if (cur < base)            gt = ~0ull;
            else if (cur - base >= 63) gt = 0ull;
            else                       gt = (~0ull) << (cur - base + 1);
            unsigned long long cand = valid & ~supp & gt;
            int idx = cand ? (base + __builtin_ctzll(cand)) : 0x7FFFFFFF;
            #pragma unroll
            for (int off = 8; off >= 1; off >>= 1) {
                int o = __shfl_xor(idx, off);
                idx = (o < idx) ? o : idx;
            }
            int nxt = __shfl(idx, 0);
            if (nxt == 0x7FFFFFFF) break;
            if (t == 0) kept[cnt] = nxt;
            ++cnt;
            if (w < 16) supp |= smask[nxt * 16 + w];
            cur = nxt;
        }
        if (t == 0) s_cnt = cnt;
    }
    __syncthreads();

    int cnt = s_cnt; if (cnt > MAX_DET) cnt = MAX_DET;
    if (t == 0) out[b] = (float)cnt;                       // num_dets (B,1)
    if (t < MAX_DET) {
        bool valid = t < cnt;
        float bx0 = 0.f, bx1 = 0.f, bx2 = 0.f, bx3 = 0.f, sc = 0.f, cl = 0.f;
        if (valid) {
            int p = kept[t];
            size_t o = (size_t)b * PRE_TOPK + p;
            float4 bb = *(const float4*)(bxyxy + o * 4);
            bx0 = bb.x; bx1 = bb.y; bx2 = bb.z; bx3 = bb.w;
            sc = sv[p];
            cl = (float)topcls[o];
        }
        size_t db = 32 + ((size_t)b * MAX_DET + t) * 4;
        out[db + 0] = bx0; out[db + 1] = bx1; out[db + 2] = bx2; out[db + 3] = bx3;
        out[32 + 12800 + (size_t)b * MAX_DET + t] = sc;    // det_scores
        out[32 + 16000 + (size_t)b * MAX_DET + t] = cl;    // det_classes
    }
}

// ---------------- launch ----------------
extern "C" void kernel_launch(void* const* d_in, const int* in_sizes, int n_in,
                              void* d_out, int out_size, void* d_ws, size_t ws_size,
                              hipStream_t stream)
{
    const float* p3 = (const float*)d_in[0];
    const float* p4 = (const float*)d_in[1];
    const float* p5 = (const float*)d_in[2];
    float* out = (float*)d_out;

    char* ws = (char*)d_ws;
    size_t off_mask = 0;                                       // 32*1000*16*8 = 4,096,000
    size_t off_conf = off_mask + (size_t)NB * PRE_TOPK * 16 * 8;
    size_t off_cls  = off_conf + (size_t)NB * NA * 4;
    size_t off_box  = off_cls  + (size_t)NB * NA * 4;
    size_t off_topv = off_box  + (size_t)NB * NA * 4 * 4;
    size_t off_topc = off_topv + (size_t)NB * PRE_TOPK * 4;
    size_t off_bx   = off_topc + (size_t)NB * PRE_TOPK * 4;

    unsigned long long* mask = (unsigned long long*)(ws + off_mask);
    float* conf   = (float*)(ws + off_conf);
    int*   clsid  = (int*)(ws + off_cls);
    float* box    = (float*)(ws + off_box);
    float* topv   = (float*)(ws + off_topv);
    int*   topcls = (int*)(ws + off_topc);
    float* bxyxy  = (float*)(ws + off_bx);

    k_decode<<<NB * 67, 512, 0, stream>>>(p3, p4, p5, conf, clsid, box);
    k_select<<<NB, 1024, 0, stream>>>(conf, box, clsid, topv, bxyxy, topcls);
    k_iou<<<dim3((PRE_TOPK + 15) / 16, NB), 256, 0, stream>>>(bxyxy, mask);
    k_nms<<<NB, 1024, 0, stream>>>(mask, topv, bxyxy, topcls, out);
}